// Round 5
// baseline (126.318 us; speedup 1.0000x reference)
//
#include <hip/hip_runtime.h>
#include <math.h>

#define N_NODES 1024
#define IN_F 512
#define N_HEADS 4
#define N_HID 32
#define OUT_F 128   // N_HEADS*N_HID
#define GF 256      // fused g row: [0..127]=g_l, [128..255]=g_r
#define NEG_SLOPE 0.2f

// ---------------- Kernel 1: LDS-tiled partial GEMM gpart[kc][row][c] -------
// (unchanged from round 4; also zeroes den for the fused kernel's atomics)
__global__ __launch_bounds__(256, 2) void gat_gemm(
    const float* __restrict__ hmat, const float* __restrict__ Wl,
    const float* __restrict__ Wr, float* __restrict__ gpart,
    float* __restrict__ den)
{
  const int b = blockIdx.x;
  if (b < 16) den[b * 256 + threadIdx.x] = 0.f;
  const int kc = b & 7, ct = (b >> 3) & 3, it = b >> 5;
  const int i0 = it * 64, k0 = kc * 64, cb0 = ct * 64;
  const float* __restrict__ W = (cb0 < 128) ? (Wl + cb0) : (Wr + (cb0 - 128));

  __shared__ float As[16][68];
  __shared__ float Bs[16][64];

  const int tx = threadIdx.x & 15, ty = threadIdx.x >> 4;
  const int ar = threadIdx.x >> 2, ak = (threadIdx.x & 3) * 4;
  const int bk = threadIdx.x >> 4, bc = (threadIdx.x & 15) * 4;

  float4 acc0 = {0.f, 0.f, 0.f, 0.f}, acc1 = acc0, acc2 = acc0, acc3 = acc0;

  float4 av = *(const float4*)(hmat + (size_t)(i0 + ar) * IN_F + k0 + ak);
  float4 bv = *(const float4*)(W + (size_t)(k0 + bk) * OUT_F + bc);

  for (int t = 0; t < 64; t += 16) {
    __syncthreads();
    As[ak + 0][ar] = av.x; As[ak + 1][ar] = av.y;
    As[ak + 2][ar] = av.z; As[ak + 3][ar] = av.w;
    *(float4*)&Bs[bk][bc] = bv;
    __syncthreads();
    if (t < 48) {
      av = *(const float4*)(hmat + (size_t)(i0 + ar) * IN_F + k0 + t + 16 + ak);
      bv = *(const float4*)(W + (size_t)(k0 + t + 16 + bk) * OUT_F + bc);
    }
#pragma unroll
    for (int k = 0; k < 16; ++k) {
      const float4 a  = *(const float4*)&As[k][ty * 4];
      const float4 bb = *(const float4*)&Bs[k][tx * 4];
      acc0.x = fmaf(a.x, bb.x, acc0.x); acc0.y = fmaf(a.x, bb.y, acc0.y);
      acc0.z = fmaf(a.x, bb.z, acc0.z); acc0.w = fmaf(a.x, bb.w, acc0.w);
      acc1.x = fmaf(a.y, bb.x, acc1.x); acc1.y = fmaf(a.y, bb.y, acc1.y);
      acc1.z = fmaf(a.y, bb.z, acc1.z); acc1.w = fmaf(a.y, bb.w, acc1.w);
      acc2.x = fmaf(a.z, bb.x, acc2.x); acc2.y = fmaf(a.z, bb.y, acc2.y);
      acc2.z = fmaf(a.z, bb.z, acc2.z); acc2.w = fmaf(a.z, bb.w, acc2.w);
      acc3.x = fmaf(a.w, bb.x, acc3.x); acc3.y = fmaf(a.w, bb.y, acc3.y);
      acc3.z = fmaf(a.w, bb.z, acc3.z); acc3.w = fmaf(a.w, bb.w, acc3.w);
    }
  }
  const size_t rbase = (size_t)kc * N_NODES + i0 + ty * 4;
  const int cc = cb0 + tx * 4;
  *(float4*)(gpart + (rbase + 0) * GF + cc) = acc0;
  *(float4*)(gpart + (rbase + 1) * GF + cc) = acc1;
  *(float4*)(gpart + (rbase + 2) * GF + cc) = acc2;
  *(float4*)(gpart + (rbase + 3) * GF + cc) = acc3;
}

// ---------------- Kernel 2: g = sum partials; alpha/beta precompute --------
// alpha_h[j] = sum_f 0.6*aw[f]*gl[j,h,f]; beta_h[i] = same on gr.
// 256 blocks x 256 thr; block = 4 rows; lane l = f4 column (64 per row).
__global__ __launch_bounds__(256) void gat_reduceWab(
    const float* __restrict__ gpart, const float* __restrict__ attn_w,
    float* __restrict__ g, float* __restrict__ abuf, float* __restrict__ bbuf)
{
  const int tid = threadIdx.x;
  const int l = tid & 63, r = tid >> 6;
  const int row = blockIdx.x * 4 + r;
  const size_t o = (size_t)row * GF + l * 4;
  float4 s = *(const float4*)(gpart + o);
#pragma unroll
  for (int c = 1; c < 8; ++c) {
    const float4 v = *(const float4*)(gpart + (size_t)c * (N_NODES * GF) + o);
    s.x += v.x; s.y += v.y; s.z += v.z; s.w += v.w;
  }
  *(float4*)(g + o) = s;
  const float4 a4 = *(const float4*)(attn_w + (l & 7) * 4);
  float d = 0.6f * (s.x * a4.x + s.y * a4.y + s.z * a4.z + s.w * a4.w);
  d += __shfl_xor(d, 1);
  d += __shfl_xor(d, 2);
  d += __shfl_xor(d, 4);
  if ((l & 7) == 0) {
    const int hq = l >> 3;  // 0..7: 0-3 -> gl (alpha), 4-7 -> gr (beta)
    if (hq < 4) abuf[hq * N_NODES + row] = d;
    else        bbuf[(hq - 4) * N_NODES + row] = d;
  }
}

// ---------------- Kernel 3: fused score + aggregate ------------------------
// e = alpha[h][j] + beta[h][i] + sum_f 0.4*aw[f]*|gl[j,f]+gr[i,f]|
// p = adj ? exp(e) : 0 ; num[i,h,f] += p*gr[j,f] ; den[h,i] += p (atomic).
// grid 512 = (jc 8 x it 64); block: i-tile 16 x 4 h x j-chunk 128.
// tid = jg(2b) | hh(2b) | il(4b). LDS gl/gr tiles f4-swizzled: the naive
// layout puts all 16 (jg,hh) lanesets on one bank-quad (h*32 floats == 0
// mod 32 banks); slot = h*8 + ((f4+jg+2h)&7) spreads them 2-per-quad (free).
__global__ __launch_bounds__(256, 2) void gat_fused(
    const float* __restrict__ g, const float* __restrict__ abuf,
    const float* __restrict__ bbuf, const float* __restrict__ attn_w,
    const int* __restrict__ adj, float* __restrict__ num_part,
    float* __restrict__ den)
{
  __shared__ float4 gl_s[32 * 32];
  __shared__ float4 gr_s[32 * 32];
  __shared__ float as_[4 * 33];

  const int b = blockIdx.x;
  const int jc = b & 7, it = b >> 3;
  const int i0 = it * 16, j0 = jc * 128;

  const int tid = threadIdx.x;
  const int jg = tid & 3, hh = (tid >> 2) & 3, il = tid >> 4;
  const int i = i0 + il;

  const int srow = tid >> 3, sf4 = tid & 7, sjg = srow >> 3;

  // persistent per-thread data
  float4 gr_i[8], c2[8];
#pragma unroll
  for (int f4 = 0; f4 < 8; ++f4) {
    gr_i[f4] = *(const float4*)(g + (size_t)i * GF + 128 + hh * N_HID + f4 * 4);
    const float4 a4 = *(const float4*)(attn_w + f4 * 4);
    c2[f4] = make_float4(0.4f * a4.x, 0.4f * a4.y, 0.4f * a4.z, 0.4f * a4.w);
  }
  const float beta = bbuf[hh * N_NODES + i];

  int slot[8], wslot[4];
#pragma unroll
  for (int f4 = 0; f4 < 8; ++f4) slot[f4] = hh * 8 + ((f4 + jg + 2 * hh) & 7);
#pragma unroll
  for (int q = 0; q < 4; ++q) wslot[q] = q * 8 + ((sf4 + sjg + 2 * q) & 7);

  // prefetch tile 0
  float4 pgl[4], pgr[4];
  float pa = 0.f;
  {
    const float* gsrc = g + (size_t)(j0 + srow) * GF;
#pragma unroll
    for (int q = 0; q < 4; ++q) {
      pgl[q] = *(const float4*)(gsrc + (sf4 + 8 * q) * 4);
      pgr[q] = *(const float4*)(gsrc + 128 + (sf4 + 8 * q) * 4);
    }
    if (tid < 128) pa = abuf[(tid >> 5) * N_NODES + j0 + (tid & 31)];
  }

  float4 num4[8];
#pragma unroll
  for (int f4 = 0; f4 < 8; ++f4) num4[f4] = make_float4(0.f, 0.f, 0.f, 0.f);
  float den_t = 0.f;

  for (int t = 0; t < 4; ++t) {
    __syncthreads();
#pragma unroll
    for (int q = 0; q < 4; ++q) {
      gl_s[srow * 32 + wslot[q]] = pgl[q];
      gr_s[srow * 32 + wslot[q]] = pgr[q];
    }
    if (tid < 128) as_[(tid >> 5) * 33 + (tid & 31)] = pa;
    __syncthreads();
    if (t < 3) {
      const float* gs2 = g + (size_t)(j0 + (t + 1) * 32 + srow) * GF;
#pragma unroll
      for (int q = 0; q < 4; ++q) {
        pgl[q] = *(const float4*)(gs2 + (sf4 + 8 * q) * 4);
        pgr[q] = *(const float4*)(gs2 + 128 + (sf4 + 8 * q) * 4);
      }
      if (tid < 128) pa = abuf[(tid >> 5) * N_NODES + j0 + (t + 1) * 32 + (tid & 31)];
    }
    const int4 ad0 = *(const int4*)(adj + (size_t)i * N_NODES + j0 + t * 32 + jg * 8);
    const int4 ad1 = *(const int4*)(adj + (size_t)i * N_NODES + j0 + t * 32 + jg * 8 + 4);
    const int* adp0 = (const int*)&ad0;
    const int* adp1 = (const int*)&ad1;

#pragma unroll
    for (int jj = 0; jj < 8; ++jj) {
      const int jl = jg * 8 + jj;
      const float4* glrow = &gl_s[jl * 32];
      const float4* grrow = &gr_s[jl * 32];
      float4 a0 = make_float4(0.f, 0.f, 0.f, 0.f), a1 = a0;
#pragma unroll
      for (int f4 = 0; f4 < 8; f4 += 2) {
        const float4 v0 = glrow[slot[f4]];
        const float4 v1 = glrow[slot[f4 + 1]];
        float sx, sy, sz, sw;
        sx = v0.x + gr_i[f4].x; sy = v0.y + gr_i[f4].y;
        sz = v0.z + gr_i[f4].z; sw = v0.w + gr_i[f4].w;
        a0.x = fmaf(c2[f4].x, __builtin_fabsf(sx), a0.x);
        a0.y = fmaf(c2[f4].y, __builtin_fabsf(sy), a0.y);
        a0.z = fmaf(c2[f4].z, __builtin_fabsf(sz), a0.z);
        a0.w = fmaf(c2[f4].w, __builtin_fabsf(sw), a0.w);
        sx = v1.x + gr_i[f4 + 1].x; sy = v1.y + gr_i[f4 + 1].y;
        sz = v1.z + gr_i[f4 + 1].z; sw = v1.w + gr_i[f4 + 1].w;
        a1.x = fmaf(c2[f4 + 1].x, __builtin_fabsf(sx), a1.x);
        a1.y = fmaf(c2[f4 + 1].y, __builtin_fabsf(sy), a1.y);
        a1.z = fmaf(c2[f4 + 1].z, __builtin_fabsf(sz), a1.z);
        a1.w = fmaf(c2[f4 + 1].w, __builtin_fabsf(sw), a1.w);
      }
      float e = ((a0.x + a0.y) + (a0.z + a0.w)) + ((a1.x + a1.y) + (a1.z + a1.w));
      e += as_[hh * 33 + jl] + beta;
      float p = __expf(e);
      const int am = (jj < 4) ? adp0[jj] : adp1[jj - 4];
      p = am ? p : 0.f;
      den_t += p;
#pragma unroll
      for (int f4 = 0; f4 < 8; ++f4) {
        const float4 gv = grrow[slot[f4]];
        num4[f4].x = fmaf(p, gv.x, num4[f4].x);
        num4[f4].y = fmaf(p, gv.y, num4[f4].y);
        num4[f4].z = fmaf(p, gv.z, num4[f4].z);
        num4[f4].w = fmaf(p, gv.w, num4[f4].w);
      }
    }
  }

  // reduce across the 4 jg lanes (lane bits 0-1)
#pragma unroll
  for (int m = 1; m < 4; m <<= 1) {
    den_t += __shfl_xor(den_t, m);
#pragma unroll
    for (int f4 = 0; f4 < 8; ++f4) {
      num4[f4].x += __shfl_xor(num4[f4].x, m);
      num4[f4].y += __shfl_xor(num4[f4].y, m);
      num4[f4].z += __shfl_xor(num4[f4].z, m);
      num4[f4].w += __shfl_xor(num4[f4].w, m);
    }
  }
  if (jg == 0) {
    float* np = num_part + ((size_t)jc * N_NODES + i) * OUT_F + hh * N_HID;
#pragma unroll
    for (int f4 = 0; f4 < 8; ++f4) *(float4*)(np + f4 * 4) = num4[f4];
    atomicAdd(&den[hh * N_NODES + i], den_t);
  }
}

// ---------------- Kernel 4: out = ELU( sum_jc num_part / den ) -------------
__global__ __launch_bounds__(256) void gat_fin(
    const float* __restrict__ num_part, const float* __restrict__ den,
    float* __restrict__ outp)
{
  const int flat = blockIdx.x * 256 + threadIdx.x;  // i*128+hf
  const int i = flat >> 7, hf = flat & 127, hh = hf >> 5;
  float t[8];
#pragma unroll
  for (int c = 0; c < 8; ++c)
    t[c] = num_part[(size_t)c * (N_NODES * OUT_F) + flat];
  float s = ((t[0] + t[1]) + (t[2] + t[3])) + ((t[4] + t[5]) + (t[6] + t[7]));
  float v = s / den[hh * N_NODES + i];
  outp[flat] = v > 0.f ? v : expm1f(v);
}

extern "C" void kernel_launch(void* const* d_in, const int* in_sizes, int n_in,
                              void* d_out, int out_size, void* d_ws, size_t ws_size,
                              hipStream_t stream) {
  const float* hmat  = (const float*)d_in[0];
  const int*   adj   = (const int*)d_in[1];
  const float* Wl    = (const float*)d_in[2];
  const float* Wr    = (const float*)d_in[3];
  const float* attnw = (const float*)d_in[4];
  float* outp = (float*)d_out;

  char* ws = (char*)d_ws;
  float* gpart = (float*)(ws);                        // 8 MB
  float* g     = (float*)(ws + (8u << 20));           // 1 MB
  float* den   = (float*)(ws + (9u << 20));           // 16 KB
  float* abuf  = (float*)(ws + (9u << 20) + (64u << 10));   // 16 KB
  float* bbuf  = (float*)(ws + (9u << 20) + (128u << 10));  // 16 KB
  float* npart = (float*)(ws + (10u << 20));          // 8 x 1024 x 128 = 4 MB

  gat_gemm<<<512, 256, 0, stream>>>(hmat, Wl, Wr, gpart, den);
  gat_reduceWab<<<256, 256, 0, stream>>>(gpart, attnw, g, abuf, bbuf);
  gat_fused<<<512, 256, 0, stream>>>(g, abuf, bbuf, attnw, adj, npart, den);
  gat_fin<<<512, 256, 0, stream>>>(npart, den, outp);
}

// Round 6
// 121.715 us; speedup vs baseline: 1.0378x; 1.0378x over previous
//
#include <hip/hip_runtime.h>
#include <math.h>

#define N_NODES 1024
#define IN_F 512
#define N_HEADS 4
#define N_HID 32
#define OUT_F 128   // N_HEADS*N_HID
#define GF 256      // fused g row: [0..127]=g_l, [128..255]=g_r
#define NEG_SLOPE 0.2f

// ---------------- Kernel 1: LDS-tiled partial GEMM gpart[kc][row][c] -------
// grid 512 = (it 16 x ct 4 x kc 8), 256 thr. BM=BN=64, k-chunk 64, TK=16.
// Thread tile 4x4; A staged transposed; next chunk reg-prefetched.
// Also zeroes den for escore's atomics.
__global__ __launch_bounds__(256, 2) void gat_gemm(
    const float* __restrict__ hmat, const float* __restrict__ Wl,
    const float* __restrict__ Wr, float* __restrict__ gpart,
    float* __restrict__ den)
{
  const int b = blockIdx.x;
  if (b < 16) den[b * 256 + threadIdx.x] = 0.f;
  const int kc = b & 7, ct = (b >> 3) & 3, it = b >> 5;
  const int i0 = it * 64, k0 = kc * 64, cb0 = ct * 64;
  const float* __restrict__ W = (cb0 < 128) ? (Wl + cb0) : (Wr + (cb0 - 128));

  __shared__ float As[16][68];
  __shared__ float Bs[16][64];

  const int tx = threadIdx.x & 15, ty = threadIdx.x >> 4;
  const int ar = threadIdx.x >> 2, ak = (threadIdx.x & 3) * 4;
  const int bk = threadIdx.x >> 4, bc = (threadIdx.x & 15) * 4;

  float4 acc0 = {0.f, 0.f, 0.f, 0.f}, acc1 = acc0, acc2 = acc0, acc3 = acc0;

  float4 av = *(const float4*)(hmat + (size_t)(i0 + ar) * IN_F + k0 + ak);
  float4 bv = *(const float4*)(W + (size_t)(k0 + bk) * OUT_F + bc);

  for (int t = 0; t < 64; t += 16) {
    __syncthreads();
    As[ak + 0][ar] = av.x; As[ak + 1][ar] = av.y;
    As[ak + 2][ar] = av.z; As[ak + 3][ar] = av.w;
    *(float4*)&Bs[bk][bc] = bv;
    __syncthreads();
    if (t < 48) {
      av = *(const float4*)(hmat + (size_t)(i0 + ar) * IN_F + k0 + t + 16 + ak);
      bv = *(const float4*)(W + (size_t)(k0 + t + 16 + bk) * OUT_F + bc);
    }
#pragma unroll
    for (int k = 0; k < 16; ++k) {
      const float4 a  = *(const float4*)&As[k][ty * 4];
      const float4 bb = *(const float4*)&Bs[k][tx * 4];
      acc0.x = fmaf(a.x, bb.x, acc0.x); acc0.y = fmaf(a.x, bb.y, acc0.y);
      acc0.z = fmaf(a.x, bb.z, acc0.z); acc0.w = fmaf(a.x, bb.w, acc0.w);
      acc1.x = fmaf(a.y, bb.x, acc1.x); acc1.y = fmaf(a.y, bb.y, acc1.y);
      acc1.z = fmaf(a.y, bb.z, acc1.z); acc1.w = fmaf(a.y, bb.w, acc1.w);
      acc2.x = fmaf(a.z, bb.x, acc2.x); acc2.y = fmaf(a.z, bb.y, acc2.y);
      acc2.z = fmaf(a.z, bb.z, acc2.z); acc2.w = fmaf(a.z, bb.w, acc2.w);
      acc3.x = fmaf(a.w, bb.x, acc3.x); acc3.y = fmaf(a.w, bb.y, acc3.y);
      acc3.z = fmaf(a.w, bb.z, acc3.z); acc3.w = fmaf(a.w, bb.w, acc3.w);
    }
  }
  const size_t rbase = (size_t)kc * N_NODES + i0 + ty * 4;
  const int cc = cb0 + tx * 4;
  *(float4*)(gpart + (rbase + 0) * GF + cc) = acc0;
  *(float4*)(gpart + (rbase + 1) * GF + cc) = acc1;
  *(float4*)(gpart + (rbase + 2) * GF + cc) = acc2;
  *(float4*)(gpart + (rbase + 3) * GF + cc) = acc3;
}

// ---------------- Kernel 2: g = sum partials; alpha/beta precompute --------
// alpha_h[j] = sum_f 0.6*aw[f]*gl[j,h,f]; beta_h[i] = same on gr.
// 256 blocks x 256 thr; block = 4 rows; lane l = f4 column (64 per row).
__global__ __launch_bounds__(256) void gat_reduceWab(
    const float* __restrict__ gpart, const float* __restrict__ attn_w,
    float* __restrict__ g, float* __restrict__ abuf, float* __restrict__ bbuf)
{
  const int tid = threadIdx.x;
  const int l = tid & 63, r = tid >> 6;
  const int row = blockIdx.x * 4 + r;
  const size_t o = (size_t)row * GF + l * 4;
  float4 s = *(const float4*)(gpart + o);
#pragma unroll
  for (int c = 1; c < 8; ++c) {
    const float4 v = *(const float4*)(gpart + (size_t)c * (N_NODES * GF) + o);
    s.x += v.x; s.y += v.y; s.z += v.z; s.w += v.w;
  }
  *(float4*)(g + o) = s;
  const float4 a4 = *(const float4*)(attn_w + (l & 7) * 4);
  float d = 0.6f * (s.x * a4.x + s.y * a4.y + s.z * a4.z + s.w * a4.w);
  d += __shfl_xor(d, 1);
  d += __shfl_xor(d, 2);
  d += __shfl_xor(d, 4);
  if ((l & 7) == 0) {
    const int hq = l >> 3;  // 0..7: 0-3 -> gl (alpha), 4-7 -> gr (beta)
    if (hq < 4) abuf[hq * N_NODES + row] = d;
    else        bbuf[(hq - 4) * N_NODES + row] = d;
  }
}

// ---------------- Kernel 3: p^T[h][j][i] = adj ? exp(e) : 0; den atomics ---
// e = alpha[h][j] + beta[h][i] + sum_f 0.4*aw[f]*|gl[j,f]+gr[i,f]|  (2 ops/f)
// grid (128 it x 32 jt), 256 thr = (jl 32, hh 4, is 2); 4 i's per thread,
// g_r rows in registers, g_l j-tile in LDS.
__global__ __launch_bounds__(256) void gat_escore(
    const float* __restrict__ g, const float* __restrict__ attn_w,
    const float* __restrict__ abuf, const float* __restrict__ bbuf,
    const int* __restrict__ adj, float* __restrict__ p, float* __restrict__ den)
{
  __shared__ float4 gls[32][33];
  const int i0 = blockIdx.x * 8;
  const int jb = blockIdx.y * 32;
  {
    const int row = threadIdx.x >> 3;
    const int f4b = threadIdx.x & 7;
#pragma unroll
    for (int q = 0; q < 4; ++q) {
      const int f4 = f4b + 8 * q;
      gls[row][f4] = *(const float4*)(g + (size_t)(jb + row) * GF + f4 * 4);
    }
  }
  const int jl = threadIdx.x & 31;
  const int hh = (threadIdx.x >> 5) & 3;
  const int is = threadIdx.x >> 7;
  const int ibase = i0 + is * 4;

  // g_r for 4 i's, this head (static indexing -> registers)
  float4 gg[4][8];
#pragma unroll
  for (int ii = 0; ii < 4; ++ii)
#pragma unroll
    for (int f4 = 0; f4 < 8; ++f4)
      gg[ii][f4] = *(const float4*)(g + (size_t)(ibase + ii) * GF + 128 +
                                    hh * N_HID + f4 * 4);
  // 0.4*aw (wave-uniform -> scalar loads)
  float4 c2[8];
#pragma unroll
  for (int f4 = 0; f4 < 8; ++f4) {
    const float4 a4 = *(const float4*)(attn_w + f4 * 4);
    c2[f4] = make_float4(0.4f * a4.x, 0.4f * a4.y, 0.4f * a4.z, 0.4f * a4.w);
  }
  const float alpha = abuf[hh * N_NODES + jb + jl];
  float beta[4];
#pragma unroll
  for (int ii = 0; ii < 4; ++ii) beta[ii] = bbuf[hh * N_NODES + ibase + ii];
  __syncthreads();

  float acc[4] = {0.f, 0.f, 0.f, 0.f};
#pragma unroll
  for (int f4 = 0; f4 < 8; ++f4) {
    const float4 gv = gls[jl][hh * 8 + f4];
#pragma unroll
    for (int ii = 0; ii < 4; ++ii) {
      float s;
      s = gv.x + gg[ii][f4].x;
      acc[ii] = fmaf(c2[f4].x, __builtin_fabsf(s), acc[ii]);
      s = gv.y + gg[ii][f4].y;
      acc[ii] = fmaf(c2[f4].y, __builtin_fabsf(s), acc[ii]);
      s = gv.z + gg[ii][f4].z;
      acc[ii] = fmaf(c2[f4].z, __builtin_fabsf(s), acc[ii]);
      s = gv.w + gg[ii][f4].w;
      acc[ii] = fmaf(c2[f4].w, __builtin_fabsf(s), acc[ii]);
    }
  }

  const int j = jb + jl;
  float4 pv;
  float* pvp = &pv.x;
#pragma unroll
  for (int ii = 0; ii < 4; ++ii) {
    const int a = adj[(size_t)(ibase + ii) * N_NODES + j];
    const float e = acc[ii] + alpha + beta[ii];
    pvp[ii] = a ? __expf(e) : 0.f;
  }
  *(float4*)(p + ((size_t)hh * N_NODES + j) * N_NODES + ibase) = pv;

  float d0 = pv.x, d1 = pv.y, d2 = pv.z, d3 = pv.w;
#pragma unroll
  for (int m = 1; m < 32; m <<= 1) {
    d0 += __shfl_xor(d0, m);
    d1 += __shfl_xor(d1, m);
    d2 += __shfl_xor(d2, m);
    d3 += __shfl_xor(d3, m);
  }
  if (jl == 0) {
    atomicAdd(&den[hh * N_NODES + ibase + 0], d0);
    atomicAdd(&den[hh * N_NODES + ibase + 1], d1);
    atomicAdd(&den[hh * N_NODES + ibase + 2], d2);
    atomicAdd(&den[hh * N_NODES + ibase + 3], d3);
  }
}

// ---------------- Kernel 4: LDS-tiled aggregation partials -----------------
// hpart[jc][i][hf] = sum_{j in 128-chunk} p^T[h][j][i] * gr[j][hf].
// grid 512 = (jc 8 x hh 4 x it 16), 256 thr = (f2 16, ig 16).
__global__ __launch_bounds__(256, 2) void gat_aggr(
    const float* __restrict__ p, const float* __restrict__ g,
    float* __restrict__ hpart)
{
  const int b = blockIdx.x;
  const int jc = b & 7, hh = (b >> 3) & 3, it = b >> 5;
  const int i0 = it * 64, j0 = jc * 128;

  __shared__ float Ps[16][64];
  __shared__ float Gs[16][32];

  const int f2 = threadIdx.x & 15, ig = threadIdx.x >> 4;
  const int pj = threadIdx.x >> 4, pi = (threadIdx.x & 15) * 4;
  const int gj = threadIdx.x >> 3, gf = (threadIdx.x & 7) * 4;

  const float* __restrict__ pbase =
      p + (size_t)hh * N_NODES * N_NODES + i0 + pi;
  const float* __restrict__ gbase = g + 128 + hh * N_HID + gf;

  float a00 = 0.f, a01 = 0.f, a10 = 0.f, a11 = 0.f;
  float a20 = 0.f, a21 = 0.f, a30 = 0.f, a31 = 0.f;

  float4 pv = *(const float4*)(pbase + (size_t)(j0 + pj) * N_NODES);
  float4 gv = {0.f, 0.f, 0.f, 0.f};
  if (threadIdx.x < 128)
    gv = *(const float4*)(gbase + (size_t)(j0 + gj) * GF);

  for (int c = 0; c < 8; ++c) {
    __syncthreads();
    *(float4*)&Ps[pj][pi] = pv;
    if (threadIdx.x < 128) *(float4*)&Gs[gj][gf] = gv;
    __syncthreads();
    if (c < 7) {
      pv = *(const float4*)(pbase + (size_t)(j0 + (c + 1) * 16 + pj) * N_NODES);
      if (threadIdx.x < 128)
        gv = *(const float4*)(gbase + (size_t)(j0 + (c + 1) * 16 + gj) * GF);
    }
#pragma unroll
    for (int k = 0; k < 16; ++k) {
      const float4 pp = *(const float4*)&Ps[k][ig * 4];
      const float2 gg = *(const float2*)&Gs[k][f2 * 2];
      a00 = fmaf(pp.x, gg.x, a00); a01 = fmaf(pp.x, gg.y, a01);
      a10 = fmaf(pp.y, gg.x, a10); a11 = fmaf(pp.y, gg.y, a11);
      a20 = fmaf(pp.z, gg.x, a20); a21 = fmaf(pp.z, gg.y, a21);
      a30 = fmaf(pp.w, gg.x, a30); a31 = fmaf(pp.w, gg.y, a31);
    }
  }
  float* hp = hpart + ((size_t)jc * N_NODES + i0 + ig * 4) * OUT_F +
              hh * N_HID + f2 * 2;
  *(float2*)(hp + 0 * OUT_F) = make_float2(a00, a01);
  *(float2*)(hp + 1 * OUT_F) = make_float2(a10, a11);
  *(float2*)(hp + 2 * OUT_F) = make_float2(a20, a21);
  *(float2*)(hp + 3 * OUT_F) = make_float2(a30, a31);
}

// ---------------- Kernel 5: out = ELU( sum_c hpart[c] / den ) --------------
__global__ __launch_bounds__(256) void gat_fin(
    const float* __restrict__ hpart, const float* __restrict__ den,
    float* __restrict__ outp)
{
  const int flat = blockIdx.x * 256 + threadIdx.x;  // i*128+hf
  const int i = flat >> 7, hf = flat & 127, hh = hf >> 5;
  float t[8];
#pragma unroll
  for (int c = 0; c < 8; ++c)
    t[c] = hpart[(size_t)c * (N_NODES * OUT_F) + flat];
  float s = ((t[0] + t[1]) + (t[2] + t[3])) + ((t[4] + t[5]) + (t[6] + t[7]));
  float v = s / den[hh * N_NODES + i];
  outp[flat] = v > 0.f ? v : expm1f(v);
}

extern "C" void kernel_launch(void* const* d_in, const int* in_sizes, int n_in,
                              void* d_out, int out_size, void* d_ws, size_t ws_size,
                              hipStream_t stream) {
  const float* hmat  = (const float*)d_in[0];
  const int*   adj   = (const int*)d_in[1];
  const float* Wl    = (const float*)d_in[2];
  const float* Wr    = (const float*)d_in[3];
  const float* attnw = (const float*)d_in[4];
  float* outp = (float*)d_out;

  char* ws = (char*)d_ws;
  float* gpart = (float*)(ws);                        // 8 MB
  float* g     = (float*)(ws + (8u << 20));           // 1 MB
  float* den   = (float*)(ws + (9u << 20));           // 16 KB
  float* abuf  = (float*)(ws + (9u << 20) + (64u << 10));   // 16 KB
  float* bbuf  = (float*)(ws + (9u << 20) + (128u << 10));  // 16 KB
  float* p     = (float*)(ws + (10u << 20));          // 16 MB
  float* hpart = (float*)(ws + (26u << 20));          // 4 MB

  gat_gemm<<<512, 256, 0, stream>>>(hmat, Wl, Wr, gpart, den);
  gat_reduceWab<<<256, 256, 0, stream>>>(gpart, attnw, g, abuf, bbuf);
  gat_escore<<<dim3(128, 32), 256, 0, stream>>>(g, attnw, abuf, bbuf, adj, p, den);
  gat_aggr<<<512, 256, 0, stream>>>(p, g, hpart);
  gat_fin<<<512, 256, 0, stream>>>(hpart, den, outp);
}